// Round 6
// baseline (361.291 us; speedup 1.0000x reference)
//
#include <hip/hip_runtime.h>

#define N_NODES 100000
#define N_EDGES 1600000

#define NBIN 196            // ceil(100000 / 512) dst-bins
#define BINCAP 9216         // mean 8163, sigma ~90 -> 11+ sigma headroom
#define NPB 4096            // edges per partition block
#define EPT 16              // NPB / 256
#define BPT 36              // BINCAP / 256
#define PBLK ((N_EDGES + NPB - 1) / NPB)   // 391

typedef unsigned int uint;
typedef unsigned short u16;
typedef unsigned long long u64;
typedef __attribute__((ext_vector_type(8))) short bf16x8;  // 8 bf16 (4 VGPRs)
typedef __attribute__((ext_vector_type(4))) float f32x4;

__device__ __forceinline__ uint bf16_rtne(float f) {
  uint u = __float_as_uint(f);
  return (u + 0x7fffu + ((u >> 16) & 1u)) >> 16;
}

// ---------------- coarse-bin counting-sort partition ----------------

__global__ __launch_bounds__(256) void k_zerobc(int* __restrict__ bin_cur) {
  if (threadIdx.x < NBIN) bin_cur[threadIdx.x] = 0;
}

// Partition edges into 196 dst-bins (512 nodes each).
// dst kept in regs across phases; wave-replicated LDS hist/cursor (4 copies).
__global__ __launch_bounds__(256) void k_part(const int* __restrict__ ei, int* __restrict__ bin_cur,
                                              uint* __restrict__ stage) {
  __shared__ uint hist[4][NBIN];
  __shared__ uint wbase[4][NBIN];
  __shared__ uint lcur[4][NBIN];
  const int t = threadIdx.x;
  const int w = t >> 6;
  const int e0 = blockIdx.x * NPB;
  for (int i = t; i < 4 * NBIN; i += 256) { (&hist[0][0])[i] = 0; (&lcur[0][0])[i] = 0; }
  __syncthreads();
  uint d[EPT];
#pragma unroll
  for (int j = 0; j < EPT; ++j) {
    int e = e0 + j * 256 + t;
    d[j] = (e < N_EDGES) ? (uint)ei[N_EDGES + e] : 0xFFFFFFFFu;
    if (d[j] != 0xFFFFFFFFu) atomicAdd(&hist[w][d[j] >> 9], 1u);
  }
  __syncthreads();
  if (t < NBIN) {
    uint h0 = hist[0][t], h1 = hist[1][t], h2 = hist[2][t], h3 = hist[3][t];
    uint tot = h0 + h1 + h2 + h3;
    uint g = tot ? (uint)atomicAdd(&bin_cur[t], (int)tot) : 0u;
    wbase[0][t] = g;
    wbase[1][t] = g + h0;
    wbase[2][t] = g + h0 + h1;
    wbase[3][t] = g + h0 + h1 + h2;
  }
  __syncthreads();
#pragma unroll
  for (int j = 0; j < EPT; ++j) {
    if (d[j] != 0xFFFFFFFFu) {
      int e = e0 + j * 256 + t;
      uint s = (uint)ei[e];
      uint b = d[j] >> 9;
      uint pos = wbase[w][b] + atomicAdd(&lcur[w][b], 1u);
      if (pos < BINCAP)  // statistically unreachable guard
        stage[(size_t)b * BINCAP + pos] = s | ((d[j] & 511u) << 17);
    }
  }
}

// scan 196 bin totals -> per-bin edge base (ebase) + rowptr[N_NODES]
__global__ __launch_bounds__(256) void k_binscan(const int* __restrict__ bin_cur,
                                                 int* __restrict__ ebase, int* __restrict__ rowptr) {
  __shared__ int sd[256];
  const int t = threadIdx.x;
  int v = (t < NBIN) ? min(bin_cur[t], BINCAP) : 0;
  int s = v;
  sd[t] = s;
  __syncthreads();
  for (int off = 1; off < 256; off <<= 1) {
    int a = (t >= off) ? sd[t - off] : 0;
    __syncthreads();
    sd[t] += a;
    __syncthreads();
  }
  if (t < NBIN) ebase[t] = sd[t] - v;
  if (t == 255) rowptr[N_NODES] = sd[255];
}

// fused bin pass: stage chunk -> regs, LDS degree count -> scan ->
// rowptr + dinv, then scatter {src, 0} into the bin's CONTIGUOUS ep region.
// (weight slot .y is patched by k_epw once all bins' dinv are final)
__global__ __launch_bounds__(256) void k_bin2(const int* __restrict__ bin_cur, const uint* __restrict__ stage,
                                              const int* __restrict__ ebase,
                                              float* __restrict__ dinv, int* __restrict__ rowptr,
                                              int2* __restrict__ ep) {
  __shared__ int cnt[512];
  __shared__ int sd[256];
  __shared__ int curs[512];
  const int b = blockIdx.x, t = threadIdx.x;
  cnt[t] = 0; cnt[t + 256] = 0;
  __syncthreads();
  const int n = min(bin_cur[b], BINCAP);
  const uint* sb = stage + (size_t)b * BINCAP;
  uint r[BPT];
#pragma unroll
  for (int j = 0; j < BPT; ++j) {
    int i = j * 256 + t;
    r[j] = (i < n) ? sb[i] : 0xFFFFFFFFu;
  }
#pragma unroll
  for (int j = 0; j < BPT; ++j)
    if (r[j] != 0xFFFFFFFFu) atomicAdd(&cnt[r[j] >> 17], 1);
  __syncthreads();
  int v0 = cnt[t * 2], v1 = cnt[t * 2 + 1];
  int s = v0 + v1;
  sd[t] = s;
  __syncthreads();
  for (int off = 1; off < 256; off <<= 1) {
    int a = (t >= off) ? sd[t - off] : 0;
    __syncthreads();
    sd[t] += a;
    __syncthreads();
  }
  int run = sd[t] - s;  // exclusive prefix of this thread's 2 nodes
  int eb = ebase[b];
  int c0 = eb + run, c1 = eb + run + v0;
  int g0 = b * 512 + t * 2;
  if (g0 < N_NODES) {
    rowptr[g0] = c0;
    dinv[g0] = rsqrtf((float)(v0 + 1));  // +1 self-loop
  }
  if (g0 + 1 < N_NODES) {
    rowptr[g0 + 1] = c1;
    dinv[g0 + 1] = rsqrtf((float)(v1 + 1));
  }
  curs[t * 2] = c0; curs[t * 2 + 1] = c1;
  __syncthreads();
#pragma unroll
  for (int j = 0; j < BPT; ++j)
    if (r[j] != 0xFFFFFFFFu) {
      int pos = atomicAdd(&curs[r[j] >> 17], 1);
      int2 pr; pr.x = (int)(r[j] & 0x1FFFFu); pr.y = 0;
      ep[pos] = pr;
    }
}

// patch ep[e].y = dinv[src] in place (dinv gather is sole traffic -> L2-hot)
__global__ __launch_bounds__(256) void k_epw(int2* __restrict__ ep, const float* __restrict__ dinv) {
  int i = blockIdx.x * 256 + threadIdx.x;
  if (i < N_EDGES) {
    int2 v = ep[i];
    v.y = __float_as_int(dinv[v.x]);
    ep[i] = v;
  }
}

// ---------------- W pre-swizzle to MFMA B-fragment order ----------------

__global__ __launch_bounds__(256) void k_prepw(const float* __restrict__ W1, const float* __restrict__ W2,
                                               uint* __restrict__ S1, uint* __restrict__ S2) {
  int u = blockIdx.x * 256 + threadIdx.x;  // 0..2047
  const float* W = blockIdx.y ? W2 : W1;
  uint* S = blockIdx.y ? S2 : S1;
  int lane = u & 63;
  int kcnt = u >> 6;
  int kc = kcnt & 3;
  int nt = kcnt >> 2;
  int n = nt * 16 + (lane & 15);
  int k0 = kc * 32 + (lane >> 4) * 8;
  float f[8];
#pragma unroll
  for (int j = 0; j < 8; ++j) f[j] = W[(size_t)(k0 + j) * 128 + n];
  uint4 pk;
  pk.x = bf16_rtne(f[0]) | (bf16_rtne(f[1]) << 16);
  pk.y = bf16_rtne(f[2]) | (bf16_rtne(f[3]) << 16);
  pk.z = bf16_rtne(f[4]) | (bf16_rtne(f[5]) << 16);
  pk.w = bf16_rtne(f[6]) | (bf16_rtne(f[7]) << 16);
  ((uint4*)S)[u] = pk;
}

// ---------------- MFMA GEMM (layer 1): hb[nrows,128](bf16) = x[nrows,128] @ W1 ----------------

__global__ __launch_bounds__(256) void k_gemm(const void* __restrict__ Ain, int a_f32,
                                              const uint* __restrict__ Wsw,
                                              u16* __restrict__ OutH, int nrows) {
  __shared__ uint As[4096];   // 16 KB A fragments
  __shared__ uint Bs[8192];   // 32 KB B fragments
  const int tid = threadIdx.x;
  const int R = blockIdx.x * 64;
  {
    const uint4* src = (const uint4*)Wsw;
    uint4* dst = (uint4*)Bs;
#pragma unroll
    for (int v = 0; v < 8; ++v) dst[tid + v * 256] = src[tid + v * 256];
  }
  const int unit = tid & 15;      // k8-slice 0..15
  const int kc_s = unit >> 2;
  const int quad_s = unit & 3;
#pragma unroll
  for (int pass = 0; pass < 4; ++pass) {
    int row = pass * 16 + (tid >> 4);
    int gr = R + row;
    if (gr >= nrows) gr = nrows - 1;
    uint4 pk;
    if (a_f32) {
      const float* srcr = (const float*)Ain + (size_t)gr * 128 + unit * 8;
      float4 f0 = ((const float4*)srcr)[0];
      float4 f1 = ((const float4*)srcr)[1];
      pk.x = bf16_rtne(f0.x) | (bf16_rtne(f0.y) << 16);
      pk.y = bf16_rtne(f0.z) | (bf16_rtne(f0.w) << 16);
      pk.z = bf16_rtne(f1.x) | (bf16_rtne(f1.y) << 16);
      pk.w = bf16_rtne(f1.z) | (bf16_rtne(f1.w) << 16);
    } else {
      pk = ((const uint4*)((const uint*)Ain + (size_t)gr * 64))[unit];
    }
    int lane_t = quad_s * 16 + (row & 15);
    *(uint4*)&As[((pass * 4 + kc_s) * 64 + lane_t) * 4] = pk;
  }
  __syncthreads();

  const int w = tid >> 6;
  const int lane = tid & 63;
  bf16x8 a0 = *(bf16x8*)&As[((w * 4 + 0) * 64 + lane) * 4];
  bf16x8 a1 = *(bf16x8*)&As[((w * 4 + 1) * 64 + lane) * 4];
  bf16x8 a2 = *(bf16x8*)&As[((w * 4 + 2) * 64 + lane) * 4];
  bf16x8 a3 = *(bf16x8*)&As[((w * 4 + 3) * 64 + lane) * 4];
  f32x4 acc[8];
#pragma unroll
  for (int nt = 0; nt < 8; ++nt) acc[nt] = (f32x4){0.f, 0.f, 0.f, 0.f};
#pragma unroll
  for (int nt = 0; nt < 8; ++nt) {
    bf16x8 b0 = *(bf16x8*)&Bs[((nt * 4 + 0) * 64 + lane) * 4];
    bf16x8 b1 = *(bf16x8*)&Bs[((nt * 4 + 1) * 64 + lane) * 4];
    bf16x8 b2 = *(bf16x8*)&Bs[((nt * 4 + 2) * 64 + lane) * 4];
    bf16x8 b3 = *(bf16x8*)&Bs[((nt * 4 + 3) * 64 + lane) * 4];
    acc[nt] = __builtin_amdgcn_mfma_f32_16x16x32_bf16(a0, b0, acc[nt], 0, 0, 0);
    acc[nt] = __builtin_amdgcn_mfma_f32_16x16x32_bf16(a1, b1, acc[nt], 0, 0, 0);
    acc[nt] = __builtin_amdgcn_mfma_f32_16x16x32_bf16(a2, b2, acc[nt], 0, 0, 0);
    acc[nt] = __builtin_amdgcn_mfma_f32_16x16x32_bf16(a3, b3, acc[nt], 0, 0, 0);
  }
  const int colb = lane & 15;
  const int quad = lane >> 4;
#pragma unroll
  for (int nt = 0; nt < 8; ++nt) {
#pragma unroll
    for (int r = 0; r < 4; ++r) {
      int gr = R + w * 16 + quad * 4 + r;
      if (gr < nrows)
        OutH[(size_t)gr * 128 + nt * 16 + colb] = (u16)bf16_rtne(acc[nt][r]);
    }
  }
}

// ---------------- helpers ----------------

__device__ __forceinline__ void bacc(float& ax, float& ay, uint v, float w) {
  ax += w * __uint_as_float(v << 16);
  ay += w * __uint_as_float(v & 0xffff0000u);
}

// nontemporal int2 load via u64 (builtin rejects HIP vector types)
__device__ __forceinline__ u64 nt_ld_pair(const int2* p) {
  return __builtin_nontemporal_load((const u64*)p);
}

// aggregate one node into (ax, ay); lane holds channels {2*lane, 2*lane+1}.
// ep stream is touch-once -> nontemporal (keeps L2 for the hb gather table).
__device__ __forceinline__ void agg_node(const uint* __restrict__ hb, const int2* __restrict__ ep,
                                         int node, int lane,
                                         int beg, int end, float dn, float& ax, float& ay) {
  uint selfv = hb[(size_t)node * 64 + lane];
  bacc(ax, ay, selfv, dn);
  int e = beg;
  for (; e + 8 <= end; e += 8) {
    u64 p[8];
#pragma unroll
    for (int j = 0; j < 8; ++j) p[j] = nt_ld_pair(&ep[e + j]);
    uint v[8];
#pragma unroll
    for (int j = 0; j < 8; ++j) v[j] = hb[(size_t)(uint)p[j] * 64 + lane];
#pragma unroll
    for (int j = 0; j < 8; ++j) bacc(ax, ay, v[j], __uint_as_float((uint)(p[j] >> 32)));
  }
  if (e + 4 <= end) {
    u64 p[4];
#pragma unroll
    for (int j = 0; j < 4; ++j) p[j] = nt_ld_pair(&ep[e + j]);
    uint v[4];
#pragma unroll
    for (int j = 0; j < 4; ++j) v[j] = hb[(size_t)(uint)p[j] * 64 + lane];
#pragma unroll
    for (int j = 0; j < 4; ++j) bacc(ax, ay, v[j], __uint_as_float((uint)(p[j] >> 32)));
    e += 4;
  }
  for (; e < end; ++e) {
    u64 p = nt_ld_pair(&ep[e]);
    uint v = hb[(size_t)(uint)p * 64 + lane];
    bacc(ax, ay, v, __uint_as_float((uint)(p >> 32)));
  }
}

// ---------------- fused agg(layer1) + GEMM(layer2) ----------------
// Block = 16 nodes (4 per wave). Aggregated rows -> 4 KB XOR-swizzled LDS
// A-tile -> 16x128 @ 128x128 MFMA GEMM, B-fragments from L2-hot wsw2.

__global__ __launch_bounds__(256) void k_aggm(const uint* __restrict__ hb, const float* __restrict__ dinv,
                                              const int* __restrict__ rowptr, const int2* __restrict__ ep,
                                              const float* __restrict__ bias, const uint* __restrict__ Wsw,
                                              u16* __restrict__ outH) {
  __shared__ uint Abf[16 * 64];   // 4 KB swizzled bf16 A-tile
  const int w = threadIdx.x >> 6;
  const int lane = threadIdx.x & 63;
  const int nb = blockIdx.x * 16;
#pragma unroll 1
  for (int j = 0; j < 4; ++j) {
    const int lr = w * 4 + j;
    const int node = nb + lr;
    const int beg = rowptr[node];
    const int end = rowptr[node + 1];
    const float dn = dinv[node];
    float ax = 0.f, ay = 0.f;
    agg_node(hb, ep, node, lane, beg, end, dn, ax, ay);
    int c = lane * 2;
    float rx = dn * ax + bias[c];
    float ry = dn * ay + bias[c + 1];
    uint pk = bf16_rtne(rx) | (bf16_rtne(ry) << 16);
    Abf[(lr * 64 + lane) ^ ((lr & 7) << 2)] = pk;   // swizzled store
  }
  __syncthreads();
  // GEMM: C[16x128] = A[16x128] @ W2 ; wave w handles n-tiles {2w, 2w+1}
  const int row = lane & 15;
  const int kq = lane >> 4;
  bf16x8 a[4];
#pragma unroll
  for (int kc = 0; kc < 4; ++kc) {
    int ui = row * 64 + kc * 16 + kq * 4;
    a[kc] = *(bf16x8*)&Abf[ui ^ ((row & 7) << 2)];
  }
  const int colb = lane & 15;
  const int quad = lane >> 4;
#pragma unroll
  for (int nt2 = 0; nt2 < 2; ++nt2) {
    const int nt = w * 2 + nt2;
    f32x4 acc = (f32x4){0.f, 0.f, 0.f, 0.f};
#pragma unroll
    for (int kc = 0; kc < 4; ++kc) {
      bf16x8 bfr = *(const bf16x8*)((const uint4*)Wsw + (nt * 4 + kc) * 64 + lane);
      acc = __builtin_amdgcn_mfma_f32_16x16x32_bf16(a[kc], bfr, acc, 0, 0, 0);
    }
#pragma unroll
    for (int r2 = 0; r2 < 4; ++r2) {
      int gr = nb + quad * 4 + r2;
      __builtin_nontemporal_store((u16)bf16_rtne(acc[r2]),
                                  outH + (size_t)gr * 128 + nt * 16 + colb);
    }
  }
}

// ---------------- Aggregation (layer 2): one wave per node -> f32 out ----------------

__global__ __launch_bounds__(256) void k_agg(const uint* __restrict__ hb, const float* __restrict__ dinv,
                                             const int* __restrict__ rowptr, const int2* __restrict__ ep,
                                             const float* __restrict__ bias,
                                             float* __restrict__ outf) {
  int wid = threadIdx.x >> 6;
  int lane = threadIdx.x & 63;
  int node = blockIdx.x * 4 + wid;
  if (node >= N_NODES) return;
  int beg = rowptr[node];
  int end = rowptr[node + 1];
  float dn = dinv[node];
  float ax = 0.f, ay = 0.f;
  agg_node(hb, ep, node, lane, beg, end, dn, ax, ay);
  int c = lane * 2;
  long long ov;
  float rx = dn * ax + bias[c];
  float ry = dn * ay + bias[c + 1];
  ov = (long long)(((u64)__float_as_uint(ry) << 32) | (u64)__float_as_uint(rx));
  __builtin_nontemporal_store(ov, (long long*)(outf + (size_t)node * 128 + c));
}

// ---------------- launch ----------------

extern "C" void kernel_launch(void* const* d_in, const int* in_sizes, int n_in,
                              void* d_out, int out_size, void* d_ws, size_t ws_size,
                              hipStream_t stream) {
  const float* x  = (const float*)d_in[0];
  const int*   ei = (const int*)d_in[1];   // int32: [0..E)=src, [E..2E)=dst
  const float* W1 = (const float*)d_in[2];
  const float* b1 = (const float*)d_in[3];
  const float* W2 = (const float*)d_in[4];
  const float* b2 = (const float*)d_in[5];
  float* out = (float*)d_out;

  char* p = (char*)d_ws;
  uint*  hb     = (uint*)p;  p += (size_t)N_NODES * 64 * sizeof(uint);            // 25.6 MB layer-1 h table
  int2*  ep     = (int2*)p;  p += (size_t)N_EDGES * sizeof(int2);                 // 12.8 MB (src, dinv[src])
  uint*  wsw1   = (uint*)p;  p += 8192 * sizeof(uint);                            // 32 KB
  uint*  wsw2   = (uint*)p;  p += 8192 * sizeof(uint);                            // 32 KB
  float* dinv   = (float*)p; p += (size_t)N_NODES * sizeof(float);                // 400 KB
  int*   rowptr = (int*)p;   p += (size_t)(N_NODES + 1) * sizeof(int);            // 400 KB
  int*   bin_cur= (int*)p;   p += (size_t)NBIN * sizeof(int);
  int*   ebase  = (int*)p;   p += (size_t)NBIN * sizeof(int);
  p = (char*)(((uintptr_t)p + 63) & ~(uintptr_t)63);
  // stage (7.2 MB) is dead after k_bin2; layer-2 h table (25.6 MB) aliases it.
  uint*  stage  = (uint*)p;
  uint*  hb2    = (uint*)p;   // total ws footprint ~65 MB

  const int GG = (N_NODES + 63) / 64;  // 1563

  k_zerobc<<<1, 256, 0, stream>>>(bin_cur);
  k_part<<<PBLK, 256, 0, stream>>>(ei, bin_cur, stage);
  k_binscan<<<1, 256, 0, stream>>>(bin_cur, ebase, rowptr);
  k_bin2<<<NBIN, 256, 0, stream>>>(bin_cur, stage, ebase, dinv, rowptr, ep);
  k_epw<<<(N_EDGES + 255) / 256, 256, 0, stream>>>(ep, dinv);
  k_prepw<<<dim3(8, 2), 256, 0, stream>>>(W1, W2, wsw1, wsw2);

  // layer 1 GEMM: hb = bf16(x @ W1)
  k_gemm<<<GG, 256, 0, stream>>>(x, 1, wsw1, (u16*)hb, N_NODES);
  // fused: h1 = agg(hb)+b1 ; hb2 = bf16(h1 @ W2)
  k_aggm<<<N_NODES / 16, 256, 0, stream>>>(hb, dinv, rowptr, ep, b1, wsw2, (u16*)hb2);
  // layer 2 aggregation -> f32 out
  k_agg<<<(N_NODES + 3) / 4, 256, 0, stream>>>(hb2, dinv, rowptr, ep, b2, out);
}

// Round 7
// 331.570 us; speedup vs baseline: 1.0896x; 1.0896x over previous
//
#include <hip/hip_runtime.h>

#define N_NODES 100000
#define N_EDGES 1600000

#define NBIN 196            // ceil(100000 / 512) dst-bins
#define BINCAP 9216         // mean 8163, sigma ~90 -> 11+ sigma headroom
#define NPB 4096            // edges per partition block
#define EPT 16              // NPB / 256
#define BPT 36              // BINCAP / 256
#define PBLK ((N_EDGES + NPB - 1) / NPB)   // 391

typedef unsigned int uint;
typedef unsigned short u16;
typedef unsigned long long u64;
typedef __attribute__((ext_vector_type(8))) short bf16x8;  // 8 bf16 (4 VGPRs)
typedef __attribute__((ext_vector_type(4))) float f32x4;

__device__ __forceinline__ uint bf16_rtne(float f) {
  uint u = __float_as_uint(f);
  return (u + 0x7fffu + ((u >> 16) & 1u)) >> 16;
}

// ---------------- coarse-bin counting-sort partition ----------------

__global__ __launch_bounds__(256) void k_zerobc(int* __restrict__ bin_cur) {
  if (threadIdx.x < NBIN) bin_cur[threadIdx.x] = 0;
}

// Partition edges into 196 dst-bins (512 nodes each).
// dst kept in regs across phases; wave-replicated LDS hist/cursor (4 copies).
__global__ __launch_bounds__(256) void k_part(const int* __restrict__ ei, int* __restrict__ bin_cur,
                                              uint* __restrict__ stage) {
  __shared__ uint hist[4][NBIN];
  __shared__ uint wbase[4][NBIN];
  __shared__ uint lcur[4][NBIN];
  const int t = threadIdx.x;
  const int w = t >> 6;
  const int e0 = blockIdx.x * NPB;
  for (int i = t; i < 4 * NBIN; i += 256) { (&hist[0][0])[i] = 0; (&lcur[0][0])[i] = 0; }
  __syncthreads();
  uint d[EPT];
#pragma unroll
  for (int j = 0; j < EPT; ++j) {
    int e = e0 + j * 256 + t;
    d[j] = (e < N_EDGES) ? (uint)ei[N_EDGES + e] : 0xFFFFFFFFu;
    if (d[j] != 0xFFFFFFFFu) atomicAdd(&hist[w][d[j] >> 9], 1u);
  }
  __syncthreads();
  if (t < NBIN) {
    uint h0 = hist[0][t], h1 = hist[1][t], h2 = hist[2][t], h3 = hist[3][t];
    uint tot = h0 + h1 + h2 + h3;
    uint g = tot ? (uint)atomicAdd(&bin_cur[t], (int)tot) : 0u;
    wbase[0][t] = g;
    wbase[1][t] = g + h0;
    wbase[2][t] = g + h0 + h1;
    wbase[3][t] = g + h0 + h1 + h2;
  }
  __syncthreads();
#pragma unroll
  for (int j = 0; j < EPT; ++j) {
    if (d[j] != 0xFFFFFFFFu) {
      int e = e0 + j * 256 + t;
      uint s = (uint)ei[e];
      uint b = d[j] >> 9;
      uint pos = wbase[w][b] + atomicAdd(&lcur[w][b], 1u);
      if (pos < BINCAP)  // statistically unreachable guard
        stage[(size_t)b * BINCAP + pos] = s | ((d[j] & 511u) << 17);
    }
  }
}

// scan 196 bin totals -> per-bin edge base (ebase) + rowptr[N_NODES]
__global__ __launch_bounds__(256) void k_binscan(const int* __restrict__ bin_cur,
                                                 int* __restrict__ ebase, int* __restrict__ rowptr) {
  __shared__ int sd[256];
  const int t = threadIdx.x;
  int v = (t < NBIN) ? min(bin_cur[t], BINCAP) : 0;
  int s = v;
  sd[t] = s;
  __syncthreads();
  for (int off = 1; off < 256; off <<= 1) {
    int a = (t >= off) ? sd[t - off] : 0;
    __syncthreads();
    sd[t] += a;
    __syncthreads();
  }
  if (t < NBIN) ebase[t] = sd[t] - v;
  if (t == 255) rowptr[N_NODES] = sd[255];
}

// fused bin pass: stage chunk -> regs, LDS degree count -> scan ->
// rowptr + dinv, then scatter {src, 0} into the bin's CONTIGUOUS ep region.
// (weight slot .y is patched by k_epw once all bins' dinv are final)
__global__ __launch_bounds__(256) void k_bin2(const int* __restrict__ bin_cur, const uint* __restrict__ stage,
                                              const int* __restrict__ ebase,
                                              float* __restrict__ dinv, int* __restrict__ rowptr,
                                              int2* __restrict__ ep) {
  __shared__ int cnt[512];
  __shared__ int sd[256];
  __shared__ int curs[512];
  const int b = blockIdx.x, t = threadIdx.x;
  cnt[t] = 0; cnt[t + 256] = 0;
  __syncthreads();
  const int n = min(bin_cur[b], BINCAP);
  const uint* sb = stage + (size_t)b * BINCAP;
  uint r[BPT];
#pragma unroll
  for (int j = 0; j < BPT; ++j) {
    int i = j * 256 + t;
    r[j] = (i < n) ? sb[i] : 0xFFFFFFFFu;
  }
#pragma unroll
  for (int j = 0; j < BPT; ++j)
    if (r[j] != 0xFFFFFFFFu) atomicAdd(&cnt[r[j] >> 17], 1);
  __syncthreads();
  int v0 = cnt[t * 2], v1 = cnt[t * 2 + 1];
  int s = v0 + v1;
  sd[t] = s;
  __syncthreads();
  for (int off = 1; off < 256; off <<= 1) {
    int a = (t >= off) ? sd[t - off] : 0;
    __syncthreads();
    sd[t] += a;
    __syncthreads();
  }
  int run = sd[t] - s;  // exclusive prefix of this thread's 2 nodes
  int eb = ebase[b];
  int c0 = eb + run, c1 = eb + run + v0;
  int g0 = b * 512 + t * 2;
  if (g0 < N_NODES) {
    rowptr[g0] = c0;
    dinv[g0] = rsqrtf((float)(v0 + 1));  // +1 self-loop
  }
  if (g0 + 1 < N_NODES) {
    rowptr[g0 + 1] = c1;
    dinv[g0 + 1] = rsqrtf((float)(v1 + 1));
  }
  curs[t * 2] = c0; curs[t * 2 + 1] = c1;
  __syncthreads();
#pragma unroll
  for (int j = 0; j < BPT; ++j)
    if (r[j] != 0xFFFFFFFFu) {
      int pos = atomicAdd(&curs[r[j] >> 17], 1);
      int2 pr; pr.x = (int)(r[j] & 0x1FFFFu); pr.y = 0;
      ep[pos] = pr;
    }
}

// patch ep[e].y = dinv[src] in place (dinv gather is sole traffic -> L2-hot)
__global__ __launch_bounds__(256) void k_epw(int2* __restrict__ ep, const float* __restrict__ dinv) {
  int i = blockIdx.x * 256 + threadIdx.x;
  if (i < N_EDGES) {
    int2 v = ep[i];
    v.y = __float_as_int(dinv[v.x]);
    ep[i] = v;
  }
}

// ---------------- W pre-swizzle to MFMA B-fragment order ----------------

__global__ __launch_bounds__(256) void k_prepw(const float* __restrict__ W1, const float* __restrict__ W2,
                                               uint* __restrict__ S1, uint* __restrict__ S2) {
  int u = blockIdx.x * 256 + threadIdx.x;  // 0..2047
  const float* W = blockIdx.y ? W2 : W1;
  uint* S = blockIdx.y ? S2 : S1;
  int lane = u & 63;
  int kcnt = u >> 6;
  int kc = kcnt & 3;
  int nt = kcnt >> 2;
  int n = nt * 16 + (lane & 15);
  int k0 = kc * 32 + (lane >> 4) * 8;
  float f[8];
#pragma unroll
  for (int j = 0; j < 8; ++j) f[j] = W[(size_t)(k0 + j) * 128 + n];
  uint4 pk;
  pk.x = bf16_rtne(f[0]) | (bf16_rtne(f[1]) << 16);
  pk.y = bf16_rtne(f[2]) | (bf16_rtne(f[3]) << 16);
  pk.z = bf16_rtne(f[4]) | (bf16_rtne(f[5]) << 16);
  pk.w = bf16_rtne(f[6]) | (bf16_rtne(f[7]) << 16);
  ((uint4*)S)[u] = pk;
}

// ---------------- MFMA GEMM (layer 1): hb[nrows,128](bf16) = x[nrows,128] @ W1 ----------------

__global__ __launch_bounds__(256) void k_gemm(const void* __restrict__ Ain, int a_f32,
                                              const uint* __restrict__ Wsw,
                                              u16* __restrict__ OutH, int nrows) {
  __shared__ uint As[4096];   // 16 KB A fragments
  __shared__ uint Bs[8192];   // 32 KB B fragments
  const int tid = threadIdx.x;
  const int R = blockIdx.x * 64;
  {
    const uint4* src = (const uint4*)Wsw;
    uint4* dst = (uint4*)Bs;
#pragma unroll
    for (int v = 0; v < 8; ++v) dst[tid + v * 256] = src[tid + v * 256];
  }
  const int unit = tid & 15;      // k8-slice 0..15
  const int kc_s = unit >> 2;
  const int quad_s = unit & 3;
#pragma unroll
  for (int pass = 0; pass < 4; ++pass) {
    int row = pass * 16 + (tid >> 4);
    int gr = R + row;
    if (gr >= nrows) gr = nrows - 1;
    uint4 pk;
    if (a_f32) {
      const float* srcr = (const float*)Ain + (size_t)gr * 128 + unit * 8;
      float4 f0 = ((const float4*)srcr)[0];
      float4 f1 = ((const float4*)srcr)[1];
      pk.x = bf16_rtne(f0.x) | (bf16_rtne(f0.y) << 16);
      pk.y = bf16_rtne(f0.z) | (bf16_rtne(f0.w) << 16);
      pk.z = bf16_rtne(f1.x) | (bf16_rtne(f1.y) << 16);
      pk.w = bf16_rtne(f1.z) | (bf16_rtne(f1.w) << 16);
    } else {
      pk = ((const uint4*)((const uint*)Ain + (size_t)gr * 64))[unit];
    }
    int lane_t = quad_s * 16 + (row & 15);
    *(uint4*)&As[((pass * 4 + kc_s) * 64 + lane_t) * 4] = pk;
  }
  __syncthreads();

  const int w = tid >> 6;
  const int lane = tid & 63;
  bf16x8 a0 = *(bf16x8*)&As[((w * 4 + 0) * 64 + lane) * 4];
  bf16x8 a1 = *(bf16x8*)&As[((w * 4 + 1) * 64 + lane) * 4];
  bf16x8 a2 = *(bf16x8*)&As[((w * 4 + 2) * 64 + lane) * 4];
  bf16x8 a3 = *(bf16x8*)&As[((w * 4 + 3) * 64 + lane) * 4];
  f32x4 acc[8];
#pragma unroll
  for (int nt = 0; nt < 8; ++nt) acc[nt] = (f32x4){0.f, 0.f, 0.f, 0.f};
#pragma unroll
  for (int nt = 0; nt < 8; ++nt) {
    bf16x8 b0 = *(bf16x8*)&Bs[((nt * 4 + 0) * 64 + lane) * 4];
    bf16x8 b1 = *(bf16x8*)&Bs[((nt * 4 + 1) * 64 + lane) * 4];
    bf16x8 b2 = *(bf16x8*)&Bs[((nt * 4 + 2) * 64 + lane) * 4];
    bf16x8 b3 = *(bf16x8*)&Bs[((nt * 4 + 3) * 64 + lane) * 4];
    acc[nt] = __builtin_amdgcn_mfma_f32_16x16x32_bf16(a0, b0, acc[nt], 0, 0, 0);
    acc[nt] = __builtin_amdgcn_mfma_f32_16x16x32_bf16(a1, b1, acc[nt], 0, 0, 0);
    acc[nt] = __builtin_amdgcn_mfma_f32_16x16x32_bf16(a2, b2, acc[nt], 0, 0, 0);
    acc[nt] = __builtin_amdgcn_mfma_f32_16x16x32_bf16(a3, b3, acc[nt], 0, 0, 0);
  }
  const int colb = lane & 15;
  const int quad = lane >> 4;
#pragma unroll
  for (int nt = 0; nt < 8; ++nt) {
#pragma unroll
    for (int r = 0; r < 4; ++r) {
      int gr = R + w * 16 + quad * 4 + r;
      if (gr < nrows)
        OutH[(size_t)gr * 128 + nt * 16 + colb] = (u16)bf16_rtne(acc[nt][r]);
    }
  }
}

// ---------------- helpers ----------------

__device__ __forceinline__ void bacc(float& ax, float& ay, uint v, float w) {
  ax += w * __uint_as_float(v << 16);
  ay += w * __uint_as_float(v & 0xffff0000u);
}

// aggregate one node into (ax, ay); lane holds channels {2*lane, 2*lane+1}.
// Plain loads throughout (R6 lesson: NT hints on short-reuse/sub-line
// streams regress on gfx950 — R3's plain version ran 71 us).
__device__ __forceinline__ void agg_node(const uint* __restrict__ hb, const int2* __restrict__ ep,
                                         int node, int lane,
                                         int beg, int end, float dn, float& ax, float& ay) {
  uint selfv = hb[(size_t)node * 64 + lane];
  bacc(ax, ay, selfv, dn);
  int e = beg;
  for (; e + 8 <= end; e += 8) {
    int2 p[8];
#pragma unroll
    for (int j = 0; j < 8; ++j) p[j] = ep[e + j];
    uint v[8];
#pragma unroll
    for (int j = 0; j < 8; ++j) v[j] = hb[(size_t)p[j].x * 64 + lane];
#pragma unroll
    for (int j = 0; j < 8; ++j) bacc(ax, ay, v[j], __int_as_float(p[j].y));
  }
  if (e + 4 <= end) {
    int2 p[4];
#pragma unroll
    for (int j = 0; j < 4; ++j) p[j] = ep[e + j];
    uint v[4];
#pragma unroll
    for (int j = 0; j < 4; ++j) v[j] = hb[(size_t)p[j].x * 64 + lane];
#pragma unroll
    for (int j = 0; j < 4; ++j) bacc(ax, ay, v[j], __int_as_float(p[j].y));
    e += 4;
  }
  for (; e < end; ++e) {
    int2 p = ep[e];
    uint v = hb[(size_t)p.x * 64 + lane];
    bacc(ax, ay, v, __int_as_float(p.y));
  }
}

// ---------------- fused agg(layer1) + GEMM(layer2) ----------------
// Block = 16 nodes (4 per wave). Aggregated rows -> 4 KB XOR-swizzled LDS
// A-tile -> 16x128 @ 128x128 MFMA GEMM, B-fragments from L2-hot wsw2.

__global__ __launch_bounds__(256) void k_aggm(const uint* __restrict__ hb, const float* __restrict__ dinv,
                                              const int* __restrict__ rowptr, const int2* __restrict__ ep,
                                              const float* __restrict__ bias, const uint* __restrict__ Wsw,
                                              u16* __restrict__ outH) {
  __shared__ uint Abf[16 * 64];   // 4 KB swizzled bf16 A-tile
  const int w = threadIdx.x >> 6;
  const int lane = threadIdx.x & 63;
  const int nb = blockIdx.x * 16;
#pragma unroll 1
  for (int j = 0; j < 4; ++j) {
    const int lr = w * 4 + j;
    const int node = nb + lr;
    const int beg = rowptr[node];
    const int end = rowptr[node + 1];
    const float dn = dinv[node];
    float ax = 0.f, ay = 0.f;
    agg_node(hb, ep, node, lane, beg, end, dn, ax, ay);
    int c = lane * 2;
    float rx = dn * ax + bias[c];
    float ry = dn * ay + bias[c + 1];
    uint pk = bf16_rtne(rx) | (bf16_rtne(ry) << 16);
    Abf[(lr * 64 + lane) ^ ((lr & 7) << 2)] = pk;   // swizzled store
  }
  __syncthreads();
  // GEMM: C[16x128] = A[16x128] @ W2 ; wave w handles n-tiles {2w, 2w+1}
  const int row = lane & 15;
  const int kq = lane >> 4;
  bf16x8 a[4];
#pragma unroll
  for (int kc = 0; kc < 4; ++kc) {
    int ui = row * 64 + kc * 16 + kq * 4;
    a[kc] = *(bf16x8*)&Abf[ui ^ ((row & 7) << 2)];
  }
  const int colb = lane & 15;
  const int quad = lane >> 4;
#pragma unroll
  for (int nt2 = 0; nt2 < 2; ++nt2) {
    const int nt = w * 2 + nt2;
    f32x4 acc = (f32x4){0.f, 0.f, 0.f, 0.f};
#pragma unroll
    for (int kc = 0; kc < 4; ++kc) {
      bf16x8 bfr = *(const bf16x8*)((const uint4*)Wsw + (nt * 4 + kc) * 64 + lane);
      acc = __builtin_amdgcn_mfma_f32_16x16x32_bf16(a[kc], bfr, acc, 0, 0, 0);
    }
#pragma unroll
    for (int r2 = 0; r2 < 4; ++r2) {
      int gr = nb + quad * 4 + r2;
      outH[(size_t)gr * 128 + nt * 16 + colb] = (u16)bf16_rtne(acc[r2]);
    }
  }
}

// ---------------- Aggregation (layer 2): one wave per node -> f32 out ----------------

__global__ __launch_bounds__(256) void k_agg(const uint* __restrict__ hb, const float* __restrict__ dinv,
                                             const int* __restrict__ rowptr, const int2* __restrict__ ep,
                                             const float* __restrict__ bias,
                                             float* __restrict__ outf) {
  int wid = threadIdx.x >> 6;
  int lane = threadIdx.x & 63;
  int node = blockIdx.x * 4 + wid;
  if (node >= N_NODES) return;
  int beg = rowptr[node];
  int end = rowptr[node + 1];
  float dn = dinv[node];
  float ax = 0.f, ay = 0.f;
  agg_node(hb, ep, node, lane, beg, end, dn, ax, ay);
  int c = lane * 2;
  float2 o;
  o.x = dn * ax + bias[c];
  o.y = dn * ay + bias[c + 1];
  *(float2*)(outf + (size_t)node * 128 + c) = o;
}

// ---------------- launch ----------------

extern "C" void kernel_launch(void* const* d_in, const int* in_sizes, int n_in,
                              void* d_out, int out_size, void* d_ws, size_t ws_size,
                              hipStream_t stream) {
  const float* x  = (const float*)d_in[0];
  const int*   ei = (const int*)d_in[1];   // int32: [0..E)=src, [E..2E)=dst
  const float* W1 = (const float*)d_in[2];
  const float* b1 = (const float*)d_in[3];
  const float* W2 = (const float*)d_in[4];
  const float* b2 = (const float*)d_in[5];
  float* out = (float*)d_out;

  char* p = (char*)d_ws;
  uint*  hb     = (uint*)p;  p += (size_t)N_NODES * 64 * sizeof(uint);            // 25.6 MB layer-1 h table
  int2*  ep     = (int2*)p;  p += (size_t)N_EDGES * sizeof(int2);                 // 12.8 MB (src, dinv[src])
  uint*  wsw1   = (uint*)p;  p += 8192 * sizeof(uint);                            // 32 KB
  uint*  wsw2   = (uint*)p;  p += 8192 * sizeof(uint);                            // 32 KB
  float* dinv   = (float*)p; p += (size_t)N_NODES * sizeof(float);                // 400 KB
  int*   rowptr = (int*)p;   p += (size_t)(N_NODES + 1) * sizeof(int);            // 400 KB
  int*   bin_cur= (int*)p;   p += (size_t)NBIN * sizeof(int);
  int*   ebase  = (int*)p;   p += (size_t)NBIN * sizeof(int);
  p = (char*)(((uintptr_t)p + 63) & ~(uintptr_t)63);
  // stage (7.2 MB) is dead after k_bin2; layer-2 h table (25.6 MB) aliases it.
  uint*  stage  = (uint*)p;
  uint*  hb2    = (uint*)p;   // total ws footprint ~65 MB

  const int GG = (N_NODES + 63) / 64;  // 1563

  k_zerobc<<<1, 256, 0, stream>>>(bin_cur);
  k_part<<<PBLK, 256, 0, stream>>>(ei, bin_cur, stage);
  k_binscan<<<1, 256, 0, stream>>>(bin_cur, ebase, rowptr);
  k_bin2<<<NBIN, 256, 0, stream>>>(bin_cur, stage, ebase, dinv, rowptr, ep);
  k_epw<<<(N_EDGES + 255) / 256, 256, 0, stream>>>(ep, dinv);
  k_prepw<<<dim3(8, 2), 256, 0, stream>>>(W1, W2, wsw1, wsw2);

  // layer 1 GEMM: hb = bf16(x @ W1)
  k_gemm<<<GG, 256, 0, stream>>>(x, 1, wsw1, (u16*)hb, N_NODES);
  // fused: h1 = agg(hb)+b1 ; hb2 = bf16(h1 @ W2)
  k_aggm<<<N_NODES / 16, 256, 0, stream>>>(hb, dinv, rowptr, ep, b1, wsw2, (u16*)hb2);
  // layer 2 aggregation -> f32 out
  k_agg<<<(N_NODES + 3) / 4, 256, 0, stream>>>(hb2, dinv, rowptr, ep, b2, out);
}

// Round 8
// 292.277 us; speedup vs baseline: 1.2361x; 1.1344x over previous
//
#include <hip/hip_runtime.h>

#define N_NODES 100000
#define N_EDGES 1600000

#define NBIN 196            // ceil(100000 / 512) dst-bins
#define BINCAP 9216         // mean 8163, sigma ~90 -> 11+ sigma headroom
#define NPB 4096            // edges per partition block
#define EPT 16              // NPB / 256
#define BPT 36              // BINCAP / 256
#define PBLK ((N_EDGES + NPB - 1) / NPB)   // 391
#define GG ((N_NODES + 63) / 64)           // 1563

typedef unsigned int uint;
typedef unsigned short u16;
typedef unsigned long long u64;
typedef __attribute__((ext_vector_type(8))) short bf16x8;  // 8 bf16 (4 VGPRs)
typedef __attribute__((ext_vector_type(4))) float f32x4;

__device__ __forceinline__ uint bf16_rtne(float f) {
  uint u = __float_as_uint(f);
  return (u + 0x7fffu + ((u >> 16) & 1u)) >> 16;
}

// ---------------- W pre-swizzle (+ bin_cur zeroing piggyback) ----------------

__global__ __launch_bounds__(256) void k_prepw(const float* __restrict__ W1, const float* __restrict__ W2,
                                               uint* __restrict__ S1, uint* __restrict__ S2,
                                               int* __restrict__ bin_cur) {
  if (blockIdx.x == 0 && blockIdx.y == 0 && threadIdx.x < NBIN) bin_cur[threadIdx.x] = 0;
  int u = blockIdx.x * 256 + threadIdx.x;  // 0..2047
  const float* W = blockIdx.y ? W2 : W1;
  uint* S = blockIdx.y ? S2 : S1;
  int lane = u & 63;
  int kcnt = u >> 6;
  int kc = kcnt & 3;
  int nt = kcnt >> 2;
  int n = nt * 16 + (lane & 15);
  int k0 = kc * 32 + (lane >> 4) * 8;
  float f[8];
#pragma unroll
  for (int j = 0; j < 8; ++j) f[j] = W[(size_t)(k0 + j) * 128 + n];
  uint4 pk;
  pk.x = bf16_rtne(f[0]) | (bf16_rtne(f[1]) << 16);
  pk.y = bf16_rtne(f[2]) | (bf16_rtne(f[3]) << 16);
  pk.z = bf16_rtne(f[4]) | (bf16_rtne(f[5]) << 16);
  pk.w = bf16_rtne(f[6]) | (bf16_rtne(f[7]) << 16);
  ((uint4*)S)[u] = pk;
}

// ---------------- fused partition || layer-1 GEMM (independent work) ----------------
// blocks [0, PBLK): counting-sort partition into 196 dst-bins
// blocks [PBLK, PBLK+GG): hb[64rows,128](bf16) = x @ W1 via MFMA
// No data deps between the halves; they overlap on different pipes.

__device__ __forceinline__ void part_body(int bid, const int* __restrict__ ei,
                                          int* __restrict__ bin_cur, uint* __restrict__ stage,
                                          uint* smem) {
  uint* hist  = smem;              // [4][NBIN]
  uint* wbase = smem + 4 * NBIN;   // [4][NBIN]
  uint* lcur  = smem + 8 * NBIN;   // [4][NBIN]
  const int t = threadIdx.x;
  const int w = t >> 6;
  const int e0 = bid * NPB;
  for (int i = t; i < 4 * NBIN; i += 256) { hist[i] = 0; lcur[i] = 0; }
  __syncthreads();
  uint d[EPT];
#pragma unroll
  for (int j = 0; j < EPT; ++j) {
    int e = e0 + j * 256 + t;
    d[j] = (e < N_EDGES) ? (uint)ei[N_EDGES + e] : 0xFFFFFFFFu;
    if (d[j] != 0xFFFFFFFFu) atomicAdd(&hist[w * NBIN + (d[j] >> 9)], 1u);
  }
  __syncthreads();
  if (t < NBIN) {
    uint h0 = hist[t], h1 = hist[NBIN + t], h2 = hist[2 * NBIN + t], h3 = hist[3 * NBIN + t];
    uint tot = h0 + h1 + h2 + h3;
    uint g = tot ? (uint)atomicAdd(&bin_cur[t], (int)tot) : 0u;
    wbase[t] = g;
    wbase[NBIN + t] = g + h0;
    wbase[2 * NBIN + t] = g + h0 + h1;
    wbase[3 * NBIN + t] = g + h0 + h1 + h2;
  }
  __syncthreads();
#pragma unroll
  for (int j = 0; j < EPT; ++j) {
    if (d[j] != 0xFFFFFFFFu) {
      int e = e0 + j * 256 + t;
      uint s = (uint)ei[e];
      uint b = d[j] >> 9;
      uint pos = wbase[w * NBIN + b] + atomicAdd(&lcur[w * NBIN + b], 1u);
      if (pos < BINCAP)  // statistically unreachable guard
        stage[(size_t)b * BINCAP + pos] = s | ((d[j] & 511u) << 17);
    }
  }
}

__device__ __forceinline__ void gemm_body(int gb, const float* __restrict__ x,
                                          const uint* __restrict__ Wsw, u16* __restrict__ OutH,
                                          uint* smem) {
  uint* As = smem;          // 16 KB A fragments
  uint* Bs = smem + 4096;   // 32 KB B fragments
  const int tid = threadIdx.x;
  const int R = gb * 64;
  {
    const uint4* src = (const uint4*)Wsw;
    uint4* dst = (uint4*)Bs;
#pragma unroll
    for (int v = 0; v < 8; ++v) dst[tid + v * 256] = src[tid + v * 256];
  }
  const int unit = tid & 15;      // k8-slice 0..15
  const int kc_s = unit >> 2;
  const int quad_s = unit & 3;
#pragma unroll
  for (int pass = 0; pass < 4; ++pass) {
    int row = pass * 16 + (tid >> 4);
    int gr = R + row;
    if (gr >= N_NODES) gr = N_NODES - 1;
    const float* srcr = x + (size_t)gr * 128 + unit * 8;
    float4 f0 = ((const float4*)srcr)[0];
    float4 f1 = ((const float4*)srcr)[1];
    uint4 pk;
    pk.x = bf16_rtne(f0.x) | (bf16_rtne(f0.y) << 16);
    pk.y = bf16_rtne(f0.z) | (bf16_rtne(f0.w) << 16);
    pk.z = bf16_rtne(f1.x) | (bf16_rtne(f1.y) << 16);
    pk.w = bf16_rtne(f1.z) | (bf16_rtne(f1.w) << 16);
    int lane_t = quad_s * 16 + (row & 15);
    *(uint4*)&As[((pass * 4 + kc_s) * 64 + lane_t) * 4] = pk;
  }
  __syncthreads();

  const int w = tid >> 6;
  const int lane = tid & 63;
  bf16x8 a0 = *(bf16x8*)&As[((w * 4 + 0) * 64 + lane) * 4];
  bf16x8 a1 = *(bf16x8*)&As[((w * 4 + 1) * 64 + lane) * 4];
  bf16x8 a2 = *(bf16x8*)&As[((w * 4 + 2) * 64 + lane) * 4];
  bf16x8 a3 = *(bf16x8*)&As[((w * 4 + 3) * 64 + lane) * 4];
  f32x4 acc[8];
#pragma unroll
  for (int nt = 0; nt < 8; ++nt) acc[nt] = (f32x4){0.f, 0.f, 0.f, 0.f};
#pragma unroll
  for (int nt = 0; nt < 8; ++nt) {
    bf16x8 b0 = *(bf16x8*)&Bs[((nt * 4 + 0) * 64 + lane) * 4];
    bf16x8 b1 = *(bf16x8*)&Bs[((nt * 4 + 1) * 64 + lane) * 4];
    bf16x8 b2 = *(bf16x8*)&Bs[((nt * 4 + 2) * 64 + lane) * 4];
    bf16x8 b3 = *(bf16x8*)&Bs[((nt * 4 + 3) * 64 + lane) * 4];
    acc[nt] = __builtin_amdgcn_mfma_f32_16x16x32_bf16(a0, b0, acc[nt], 0, 0, 0);
    acc[nt] = __builtin_amdgcn_mfma_f32_16x16x32_bf16(a1, b1, acc[nt], 0, 0, 0);
    acc[nt] = __builtin_amdgcn_mfma_f32_16x16x32_bf16(a2, b2, acc[nt], 0, 0, 0);
    acc[nt] = __builtin_amdgcn_mfma_f32_16x16x32_bf16(a3, b3, acc[nt], 0, 0, 0);
  }
  const int colb = lane & 15;
  const int quad = lane >> 4;
#pragma unroll
  for (int nt = 0; nt < 8; ++nt) {
#pragma unroll
    for (int r = 0; r < 4; ++r) {
      int gr = R + w * 16 + quad * 4 + r;
      if (gr < N_NODES)
        OutH[(size_t)gr * 128 + nt * 16 + colb] = (u16)bf16_rtne(acc[nt][r]);
    }
  }
}

__global__ __launch_bounds__(256) void k_pg(const int* __restrict__ ei, int* __restrict__ bin_cur,
                                            uint* __restrict__ stage,
                                            const float* __restrict__ x, const uint* __restrict__ Wsw,
                                            u16* __restrict__ OutH) {
  __shared__ uint smem[12288];   // 48 KB: gemm As+Bs; part uses first 9.4 KB
  if ((int)blockIdx.x < PBLK) part_body(blockIdx.x, ei, bin_cur, stage, smem);
  else                        gemm_body(blockIdx.x - PBLK, x, Wsw, OutH, smem);
}

// ---------------- fused bin pass (+ inline 196-bin scan) ----------------
// stage chunk -> regs, global bin scan -> ebase, LDS degree count -> scan ->
// rowptr + dinv, then scatter src (int) into the bin's CONTIGUOUS ep region.

__global__ __launch_bounds__(256) void k_bin2(const int* __restrict__ bin_cur, const uint* __restrict__ stage,
                                              float* __restrict__ dinv, int* __restrict__ rowptr,
                                              int* __restrict__ ep) {
  __shared__ int cnt[512];
  __shared__ int sd[256];
  __shared__ int curs[512];
  const int b = blockIdx.x, t = threadIdx.x;
  // inline exclusive scan over all 196 bin totals (replaces k_binscan)
  int vg = (t < NBIN) ? min(bin_cur[t], BINCAP) : 0;
  sd[t] = vg;
  __syncthreads();
  for (int off = 1; off < 256; off <<= 1) {
    int a = (t >= off) ? sd[t - off] : 0;
    __syncthreads();
    sd[t] += a;
    __syncthreads();
  }
  const int eb = (b > 0) ? sd[b - 1] : 0;
  if (b == 0 && t == 0) rowptr[N_NODES] = sd[NBIN - 1];
  __syncthreads();  // sd reused below

  cnt[t] = 0; cnt[t + 256] = 0;
  __syncthreads();
  const int n = min(bin_cur[b], BINCAP);
  const uint* sb = stage + (size_t)b * BINCAP;
  uint r[BPT];
#pragma unroll
  for (int j = 0; j < BPT; ++j) {
    int i = j * 256 + t;
    r[j] = (i < n) ? sb[i] : 0xFFFFFFFFu;
  }
#pragma unroll
  for (int j = 0; j < BPT; ++j)
    if (r[j] != 0xFFFFFFFFu) atomicAdd(&cnt[r[j] >> 17], 1);
  __syncthreads();
  int v0 = cnt[t * 2], v1 = cnt[t * 2 + 1];
  int s = v0 + v1;
  sd[t] = s;
  __syncthreads();
  for (int off = 1; off < 256; off <<= 1) {
    int a = (t >= off) ? sd[t - off] : 0;
    __syncthreads();
    sd[t] += a;
    __syncthreads();
  }
  int run = sd[t] - s;  // exclusive prefix of this thread's 2 nodes
  int c0 = eb + run, c1 = eb + run + v0;
  int g0 = b * 512 + t * 2;
  if (g0 < N_NODES) {
    rowptr[g0] = c0;
    dinv[g0] = rsqrtf((float)(v0 + 1));  // +1 self-loop
  }
  if (g0 + 1 < N_NODES) {
    rowptr[g0 + 1] = c1;
    dinv[g0 + 1] = rsqrtf((float)(v1 + 1));
  }
  curs[t * 2] = c0; curs[t * 2 + 1] = c1;
  __syncthreads();
#pragma unroll
  for (int j = 0; j < BPT; ++j)
    if (r[j] != 0xFFFFFFFFu) {
      int pos = atomicAdd(&curs[r[j] >> 17], 1);
      ep[pos] = (int)(r[j] & 0x1FFFFu);
    }
}

// ---------------- helpers ----------------

__device__ __forceinline__ void bacc(float& ax, float& ay, uint v, float w) {
  ax += w * __uint_as_float(v << 16);
  ay += w * __uint_as_float(v & 0xffff0000u);
}

// aggregate one node into (ax, ay); lane holds channels {2*lane, 2*lane+1}.
// ep = src only (4 B); weight via dinv[src] gather (400 KB, ~L2-resident:
// costs ~7 MB FETCH — R4's regression was hb2 misalignment, not this).
__device__ __forceinline__ void agg_node(const uint* __restrict__ hb, const float* __restrict__ dinv,
                                         const int* __restrict__ ep, int node, int lane,
                                         int beg, int end, float dn, float& ax, float& ay) {
  uint selfv = hb[(size_t)node * 64 + lane];
  bacc(ax, ay, selfv, dn);
  int e = beg;
  for (; e + 8 <= end; e += 8) {
    int p[8];
#pragma unroll
    for (int j = 0; j < 8; ++j) p[j] = ep[e + j];
    float wt[8];
#pragma unroll
    for (int j = 0; j < 8; ++j) wt[j] = dinv[p[j]];
    uint v[8];
#pragma unroll
    for (int j = 0; j < 8; ++j) v[j] = hb[(size_t)p[j] * 64 + lane];
#pragma unroll
    for (int j = 0; j < 8; ++j) bacc(ax, ay, v[j], wt[j]);
  }
  if (e + 4 <= end) {
    int p[4];
#pragma unroll
    for (int j = 0; j < 4; ++j) p[j] = ep[e + j];
    float wt[4];
#pragma unroll
    for (int j = 0; j < 4; ++j) wt[j] = dinv[p[j]];
    uint v[4];
#pragma unroll
    for (int j = 0; j < 4; ++j) v[j] = hb[(size_t)p[j] * 64 + lane];
#pragma unroll
    for (int j = 0; j < 4; ++j) bacc(ax, ay, v[j], wt[j]);
    e += 4;
  }
  for (; e < end; ++e) {
    int p = ep[e];
    float wt = dinv[p];
    uint v = hb[(size_t)p * 64 + lane];
    bacc(ax, ay, v, wt);
  }
}

// ---------------- fused agg(layer1) + GEMM(layer2) ----------------
// Block = 16 nodes (4 per wave). Aggregated rows -> 4 KB XOR-swizzled LDS
// A-tile -> 16x128 @ 128x128 MFMA GEMM, B-fragments from L2-hot wsw2.

__global__ __launch_bounds__(256) void k_aggm(const uint* __restrict__ hb, const float* __restrict__ dinv,
                                              const int* __restrict__ rowptr, const int* __restrict__ ep,
                                              const float* __restrict__ bias, const uint* __restrict__ Wsw,
                                              u16* __restrict__ outH) {
  __shared__ uint Abf[16 * 64];   // 4 KB swizzled bf16 A-tile
  const int w = threadIdx.x >> 6;
  const int lane = threadIdx.x & 63;
  const int nb = blockIdx.x * 16;
#pragma unroll 1
  for (int j = 0; j < 4; ++j) {
    const int lr = w * 4 + j;
    const int node = nb + lr;
    const int beg = rowptr[node];
    const int end = rowptr[node + 1];
    const float dn = dinv[node];
    float ax = 0.f, ay = 0.f;
    agg_node(hb, dinv, ep, node, lane, beg, end, dn, ax, ay);
    int c = lane * 2;
    float rx = dn * ax + bias[c];
    float ry = dn * ay + bias[c + 1];
    uint pk = bf16_rtne(rx) | (bf16_rtne(ry) << 16);
    Abf[(lr * 64 + lane) ^ ((lr & 7) << 2)] = pk;   // swizzled store
  }
  __syncthreads();
  // GEMM: C[16x128] = A[16x128] @ W2 ; wave w handles n-tiles {2w, 2w+1}
  const int row = lane & 15;
  const int kq = lane >> 4;
  bf16x8 a[4];
#pragma unroll
  for (int kc = 0; kc < 4; ++kc) {
    int ui = row * 64 + kc * 16 + kq * 4;
    a[kc] = *(bf16x8*)&Abf[ui ^ ((row & 7) << 2)];
  }
  const int colb = lane & 15;
  const int quad = lane >> 4;
#pragma unroll
  for (int nt2 = 0; nt2 < 2; ++nt2) {
    const int nt = w * 2 + nt2;
    f32x4 acc = (f32x4){0.f, 0.f, 0.f, 0.f};
#pragma unroll
    for (int kc = 0; kc < 4; ++kc) {
      bf16x8 bfr = *(const bf16x8*)((const uint4*)Wsw + (nt * 4 + kc) * 64 + lane);
      acc = __builtin_amdgcn_mfma_f32_16x16x32_bf16(a[kc], bfr, acc, 0, 0, 0);
    }
#pragma unroll
    for (int r2 = 0; r2 < 4; ++r2) {
      int gr = nb + quad * 4 + r2;
      outH[(size_t)gr * 128 + nt * 16 + colb] = (u16)bf16_rtne(acc[r2]);
    }
  }
}

// ---------------- Aggregation (layer 2): one wave per node -> f32 out ----------------

__global__ __launch_bounds__(256) void k_agg(const uint* __restrict__ hb, const float* __restrict__ dinv,
                                             const int* __restrict__ rowptr, const int* __restrict__ ep,
                                             const float* __restrict__ bias,
                                             float* __restrict__ outf) {
  int wid = threadIdx.x >> 6;
  int lane = threadIdx.x & 63;
  int node = blockIdx.x * 4 + wid;
  if (node >= N_NODES) return;
  int beg = rowptr[node];
  int end = rowptr[node + 1];
  float dn = dinv[node];
  float ax = 0.f, ay = 0.f;
  agg_node(hb, dinv, ep, node, lane, beg, end, dn, ax, ay);
  int c = lane * 2;
  float2 o;
  o.x = dn * ax + bias[c];
  o.y = dn * ay + bias[c + 1];
  *(float2*)(outf + (size_t)node * 128 + c) = o;
}

// ---------------- launch ----------------

extern "C" void kernel_launch(void* const* d_in, const int* in_sizes, int n_in,
                              void* d_out, int out_size, void* d_ws, size_t ws_size,
                              hipStream_t stream) {
  const float* x  = (const float*)d_in[0];
  const int*   ei = (const int*)d_in[1];   // int32: [0..E)=src, [E..2E)=dst
  const float* W1 = (const float*)d_in[2];
  const float* b1 = (const float*)d_in[3];
  const float* W2 = (const float*)d_in[4];
  const float* b2 = (const float*)d_in[5];
  float* out = (float*)d_out;

  char* p = (char*)d_ws;
  uint*  hb     = (uint*)p;  p += (size_t)N_NODES * 64 * sizeof(uint);            // 25.6 MB layer-1 h table
  int*   ep     = (int*)p;   p += (size_t)N_EDGES * sizeof(int);                  // 6.4 MB (src only)
  uint*  wsw1   = (uint*)p;  p += 8192 * sizeof(uint);                            // 32 KB
  uint*  wsw2   = (uint*)p;  p += 8192 * sizeof(uint);                            // 32 KB
  float* dinv   = (float*)p; p += (size_t)N_NODES * sizeof(float);                // 400 KB
  int*   rowptr = (int*)p;   p += (size_t)(N_NODES + 1) * sizeof(int);            // 400 KB
  int*   bin_cur= (int*)p;   p += (size_t)NBIN * sizeof(int);
  // 256-B align the alias region: hb2 rows are 256 B; a 128-B-line-straddling
  // base inflates gather FETCH by 1.5x (R4/R7 lesson — diagnosed from counters).
  p = (char*)(((uintptr_t)p + 255) & ~(uintptr_t)255);
  // stage (7.2 MB) is dead after k_bin2; layer-2 h table (25.6 MB) aliases it.
  uint*  stage  = (uint*)p;
  uint*  hb2    = (uint*)p;   // total ws footprint ~59 MB

  k_prepw<<<dim3(8, 2), 256, 0, stream>>>(W1, W2, wsw1, wsw2, bin_cur);
  // fused: edge partition (391 blocks) || layer-1 GEMM (1563 blocks)
  k_pg<<<PBLK + GG, 256, 0, stream>>>(ei, bin_cur, stage, x, wsw1, (u16*)hb);
  k_bin2<<<NBIN, 256, 0, stream>>>(bin_cur, stage, dinv, rowptr, ep);
  // fused: h1 = agg(hb)+b1 ; hb2 = bf16(h1 @ W2)
  k_aggm<<<N_NODES / 16, 256, 0, stream>>>(hb, dinv, rowptr, ep, b1, wsw2, (u16*)hb2);
  // layer 2 aggregation -> f32 out
  k_agg<<<(N_NODES + 3) / 4, 256, 0, stream>>>(hb2, dinv, rowptr, ep, b2, out);
}